// Round 1
// baseline (1475.055 us; speedup 1.0000x reference)
//
#include <hip/hip_runtime.h>
#include <cstdint>
#include <cstddef>

#define M_DIM 8192
#define N_DIM 11008
#define K_DIM 4096

typedef __attribute__((ext_vector_type(8))) short short8;
typedef __attribute__((ext_vector_type(4))) float floatx4;
typedef __attribute__((ext_vector_type(8))) unsigned short ushort8;

// RNE fp32 -> bf16 (no NaN handling needed: inputs are finite normals)
__device__ __forceinline__ unsigned short f2bf(float f) {
    unsigned int u = __float_as_uint(f);
    unsigned int r = (u + 0x7fffu + ((u >> 16) & 1u)) >> 16;
    return (unsigned short)r;
}

__device__ __forceinline__ void gl_lds16(const unsigned short* g, unsigned short* l) {
    __builtin_amdgcn_global_load_lds(
        (const __attribute__((address_space(1))) void*)g,
        (__attribute__((address_space(3))) void*)l,
        16, 0, 0);
}

// ---------------- prepass: fp32 -> bf16 ----------------
__global__ __launch_bounds__(256) void cvt_f32_bf16(const float* __restrict__ in,
                                                    unsigned short* __restrict__ out) {
    size_t i = ((size_t)blockIdx.x * 256 + threadIdx.x) * 8;
    float4 v0 = *(const float4*)(in + i);
    float4 v1 = *(const float4*)(in + i + 4);
    ushort8 o;
    o[0] = f2bf(v0.x); o[1] = f2bf(v0.y); o[2] = f2bf(v0.z); o[3] = f2bf(v0.w);
    o[4] = f2bf(v1.x); o[5] = f2bf(v1.y); o[6] = f2bf(v1.z); o[7] = f2bf(v1.w);
    *(ushort8*)(out + i) = o;
}

// ---------------- prepass: int32 (values in [-128,127]) -> bf16 (exact) ----------------
__global__ __launch_bounds__(256) void cvt_i32_bf16(const int* __restrict__ in,
                                                    unsigned short* __restrict__ out) {
    size_t i = ((size_t)blockIdx.x * 256 + threadIdx.x) * 8;
    int4 v0 = *(const int4*)(in + i);
    int4 v1 = *(const int4*)(in + i + 4);
    ushort8 o;
    o[0] = f2bf((float)v0.x); o[1] = f2bf((float)v0.y);
    o[2] = f2bf((float)v0.z); o[3] = f2bf((float)v0.w);
    o[4] = f2bf((float)v1.x); o[5] = f2bf((float)v1.y);
    o[6] = f2bf((float)v1.z); o[7] = f2bf((float)v1.w);
    *(ushort8*)(out + i) = o;
}

// ---------------- main GEMM: m97-style 128x128 tile, BK=32 ----------------
// A: [M][K] bf16 row-major. W: [N][K] bf16 row-major (i.e. B^T layout).
// out[m][n] = (sum_k A[m][k]*W[n][k]) * scale[n] + bias[n]
__global__ __launch_bounds__(256) void gemm_bf16(
    const unsigned short* __restrict__ A,
    const unsigned short* __restrict__ W,
    const float* __restrict__ scale,
    const float* __restrict__ bias,
    float* __restrict__ out)
{
    __shared__ __align__(16) unsigned short As[128 * 32];
    __shared__ __align__(16) unsigned short Bs[128 * 32];

    const int tid  = threadIdx.x;
    const int wave = tid >> 6;
    const int lane = tid & 63;

    const int nt = blockIdx.x;   // 0..85
    const int mt = blockIdx.y;   // 0..63

    // ---- staging geometry: tile is [128 rows][32 k] bf16 = 8192 B = 8 chunks x 1024 B.
    // Each wave issues 2 global_load_lds calls (chunks wave and wave+4).
    // HW places lane data at (uniform LDS base) + lane*16 B, which equals
    // row-major [row][k]: row = chunk*16 + lane/4, kofs = (lane&3)*8 elems.
    const int srow = lane >> 2;
    const int skof = (lane & 3) * 8;
    const int c0 = wave;
    const int c1 = wave + 4;

    const unsigned short* gA0 = A + (size_t)(mt * 128 + c0 * 16 + srow) * K_DIM + skof;
    const unsigned short* gA1 = A + (size_t)(mt * 128 + c1 * 16 + srow) * K_DIM + skof;
    const unsigned short* gB0 = W + (size_t)(nt * 128 + c0 * 16 + srow) * K_DIM + skof;
    const unsigned short* gB1 = W + (size_t)(nt * 128 + c1 * 16 + srow) * K_DIM + skof;

    unsigned short* lA0 = &As[c0 * 512];   // wave-uniform
    unsigned short* lA1 = &As[c1 * 512];
    unsigned short* lB0 = &Bs[c0 * 512];
    unsigned short* lB1 = &Bs[c1 * 512];

    // ---- fragment geometry: wave (wm,wn) owns 64x64; 4x4 tiles of 16x16x32.
    // A-operand: lane holds A[m=lane&15][k=(lane>>4)*8 + j]
    // B-operand: lane holds B[k=(lane>>4)*8 + j][n=lane&15] = W-row (lane&15)
    const int mwave = (wave >> 1) * 64;
    const int nwave = (wave & 1) * 64;
    const int frow  = lane & 15;
    const int fk    = (lane >> 4) * 8;

    const unsigned short* pa[4];
    const unsigned short* pb[4];
#pragma unroll
    for (int i = 0; i < 4; ++i) pa[i] = &As[(mwave + i * 16 + frow) * 32 + fk];
#pragma unroll
    for (int j = 0; j < 4; ++j) pb[j] = &Bs[(nwave + j * 16 + frow) * 32 + fk];

    floatx4 acc[4][4];
#pragma unroll
    for (int i = 0; i < 4; ++i)
#pragma unroll
        for (int j = 0; j < 4; ++j) acc[i][j] = {0.f, 0.f, 0.f, 0.f};

    for (int kt = 0; kt < K_DIM / 32; ++kt) {
        __syncthreads();   // previous iter's ds_reads done before overwrite
        gl_lds16(gA0, lA0);
        gl_lds16(gA1, lA1);
        gl_lds16(gB0, lB0);
        gl_lds16(gB1, lB1);
        gA0 += 32; gA1 += 32; gB0 += 32; gB1 += 32;
        __syncthreads();   // staging complete (compiler drains vmcnt before barrier)

        short8 a[4], b[4];
#pragma unroll
        for (int i = 0; i < 4; ++i) a[i] = *(const short8*)pa[i];
#pragma unroll
        for (int j = 0; j < 4; ++j) b[j] = *(const short8*)pb[j];
#pragma unroll
        for (int i = 0; i < 4; ++i)
#pragma unroll
            for (int j = 0; j < 4; ++j)
                acc[i][j] = __builtin_amdgcn_mfma_f32_16x16x32_bf16(a[i], b[j], acc[i][j], 0, 0, 0);
    }

    // ---- epilogue: C/D layout col=lane&15, row=(lane>>4)*4+reg  [m89-verified]
    const int orow0 = mt * 128 + mwave + ((lane >> 4) << 2);
    const int ocol0 = nt * 128 + nwave + (lane & 15);
#pragma unroll
    for (int j = 0; j < 4; ++j) {
        const int col = ocol0 + j * 16;
        const float sc = scale[col];
        const float bz = bias[col];
#pragma unroll
        for (int i = 0; i < 4; ++i) {
            size_t base = (size_t)(orow0 + i * 16) * N_DIM + col;
            out[base]             = acc[i][j][0] * sc + bz;
            out[base + N_DIM]     = acc[i][j][1] * sc + bz;
            out[base + 2 * N_DIM] = acc[i][j][2] * sc + bz;
            out[base + 3 * N_DIM] = acc[i][j][3] * sc + bz;
        }
    }
}

// ---------------- correctness fallback if workspace is too small ----------------
__global__ __launch_bounds__(256) void naive_kernel(
    const float* __restrict__ A,
    const int* __restrict__ W,
    const float* __restrict__ scale,
    const float* __restrict__ bias,
    float* __restrict__ out)
{
    const int n = blockIdx.x * 256 + threadIdx.x;
    const int m = blockIdx.y;
    const float* a = A + (size_t)m * K_DIM;
    const int* w = W + (size_t)n * K_DIM;
    float acc = 0.f;
    for (int k = 0; k < K_DIM; ++k) acc += a[k] * (float)w[k];
    out[(size_t)m * N_DIM + n] = acc * scale[n] + bias[n];
}

extern "C" void kernel_launch(void* const* d_in, const int* in_sizes, int n_in,
                              void* d_out, int out_size, void* d_ws, size_t ws_size,
                              hipStream_t stream) {
    const float* input  = (const float*)d_in[0];   // [4,2048,4096] fp32
    const int*   weight = (const int*)d_in[1];     // [11008,4096] int (values -128..127)
    const float* scale  = (const float*)d_in[2];   // [11008]
    const float* bias   = (const float*)d_in[3];   // [1,11008]
    float* out = (float*)d_out;

    const size_t nA = (size_t)M_DIM * K_DIM;       // 33,554,432
    const size_t nW = (size_t)N_DIM * K_DIM;       // 45,088,768
    const size_t need = nA * 2 + nW * 2;           // 157.3 MB bf16 workspace

    if (ws_size >= need) {
        unsigned short* wsA = (unsigned short*)d_ws;
        unsigned short* wsW = wsA + nA;
        cvt_f32_bf16<<<dim3((unsigned)(nA / (256 * 8))), 256, 0, stream>>>(input, wsA);
        cvt_i32_bf16<<<dim3((unsigned)(nW / (256 * 8))), 256, 0, stream>>>(weight, wsW);
        gemm_bf16<<<dim3(N_DIM / 128, M_DIM / 128), 256, 0, stream>>>(wsA, wsW, scale, bias, out);
    } else {
        naive_kernel<<<dim3(N_DIM / 256, M_DIM), 256, 0, stream>>>(input, weight, scale, bias, out);
    }
}